// Round 1
// baseline (937.450 us; speedup 1.0000x reference)
//
#include <hip/hip_runtime.h>
#include <math.h>

// Problem constants (match reference)
static constexpr int kN     = 50000;
static constexpr int kFIn   = 128;
static constexpr int kHid   = 32;
static constexpr int kHeads = 4;

__device__ __forceinline__ float lrelu(float x) { return x > 0.f ? x : 0.2f * x; }

// atomic float max supporting mixed signs; init value must be -INF
__device__ __forceinline__ void atomicMaxF(float* addr, float v) {
    if (v >= 0.f) atomicMax((int*)addr, __float_as_int(v));
    else          atomicMin((unsigned int*)addr, __float_as_uint(v));
}

// ---- init: zero the accumulators, -inf the segment-max buffers ----
__global__ void k_init(float* __restrict__ zero_base, int nzero,
                       float* __restrict__ inf_base, int ninf) {
    int i = blockIdx.x * blockDim.x + threadIdx.x;
    if (i < nzero) zero_base[i] = 0.f;
    if (i < ninf)  inf_base[i]  = -INFINITY;
}

// ---- layer 1 node transform: h1 = x@W1, plus per-head attention logits ----
__global__ void k_gemm1(const float* __restrict__ x, const float* __restrict__ W1,
                        const float* __restrict__ a_src1, const float* __restrict__ a_dst1,
                        float* __restrict__ h1, float* __restrict__ asrc, float* __restrict__ adst) {
    const int n = blockIdx.x;
    const int j = threadIdx.x;            // 0..127 ; head = j>>5, chan = j&31
    __shared__ float xs[kFIn];
    xs[j] = x[n * kFIn + j];
    __syncthreads();
    float acc = 0.f;
#pragma unroll 8
    for (int k = 0; k < kFIn; ++k) acc += xs[k] * W1[k * 128 + j];
    h1[n * 128 + j] = acc;
    // per-head dot with a_src1/a_dst1 (heads are 32-lane groups inside a wave64)
    float ps = acc * a_src1[j];
    float pd = acc * a_dst1[j];
#pragma unroll
    for (int off = 16; off >= 1; off >>= 1) {
        ps += __shfl_xor(ps, off, 64);
        pd += __shfl_xor(pd, off, 64);
    }
    if ((j & 31) == 0) {
        asrc[n * kHeads + (j >> 5)] = ps;
        adst[n * kHeads + (j >> 5)] = pd;
    }
}

// ---- layer 1 edge passes ----
__global__ void k_edge_max1(const int* __restrict__ ei, int E,
                            const float* __restrict__ asrc, const float* __restrict__ adst,
                            float* __restrict__ emax) {
    int i = blockIdx.x * blockDim.x + threadIdx.x;
    int total = E + kN;
    if (i >= total) return;
    int s, d;
    if (i < E) { s = ei[i]; d = ei[E + i]; } else { s = d = i - E; }
#pragma unroll
    for (int h = 0; h < kHeads; ++h) {
        float e = lrelu(asrc[s * kHeads + h] + adst[d * kHeads + h]);
        atomicMaxF(&emax[d * kHeads + h], e);
    }
}

__global__ void k_edge_expsum1(const int* __restrict__ ei, int E,
                               const float* __restrict__ asrc, const float* __restrict__ adst,
                               const float* __restrict__ emax, float* __restrict__ denom) {
    int i = blockIdx.x * blockDim.x + threadIdx.x;
    int total = E + kN;
    if (i >= total) return;
    int s, d;
    if (i < E) { s = ei[i]; d = ei[E + i]; } else { s = d = i - E; }
#pragma unroll
    for (int h = 0; h < kHeads; ++h) {
        float e = lrelu(asrc[s * kHeads + h] + adst[d * kHeads + h]);
        atomicAdd(&denom[d * kHeads + h], expf(e - emax[d * kHeads + h]));
    }
}

// one thread per (edge, j) ; j = head*32 + chan
__global__ void k_edge_agg1(const int* __restrict__ ei, int E,
                            const float* __restrict__ asrc, const float* __restrict__ adst,
                            const float* __restrict__ emax, const float* __restrict__ denom,
                            const float* __restrict__ h1, float* __restrict__ acc1) {
    unsigned gid = blockIdx.x * blockDim.x + threadIdx.x;
    unsigned total = (unsigned)(E + kN) * 128u;
    if (gid >= total) return;
    int i = (int)(gid >> 7);
    int j = (int)(gid & 127u);
    int s, d;
    if (i < E) { s = ei[i]; d = ei[E + i]; } else { s = d = i - E; }
    int h = j >> 5;
    float e     = lrelu(asrc[s * kHeads + h] + adst[d * kHeads + h]);
    float alpha = expf(e - emax[d * kHeads + h]) / denom[d * kHeads + h];
    atomicAdd(&acc1[d * 128 + j], h1[s * 128 + j] * alpha);
}

// mean over heads + bias + ELU -> x1[N,32]
__global__ void k_finish1(const float* __restrict__ acc1, const float* __restrict__ b1,
                          float* __restrict__ x1) {
    int i = blockIdx.x * blockDim.x + threadIdx.x;
    if (i >= kN * kHid) return;
    int n = i >> 5, c = i & 31;
    float sv = 0.f;
#pragma unroll
    for (int h = 0; h < kHeads; ++h) sv += acc1[n * 128 + h * 32 + c];
    sv = sv * 0.25f + b1[c];
    x1[i] = sv > 0.f ? sv : expf(sv) - 1.f;
}

// ---- layer 2 node transform: h2[n] = dot(x1[n], W2) ----
__global__ void k_node2(const float* __restrict__ x1, const float* __restrict__ W2,
                        float* __restrict__ h2) {
    int t = blockIdx.x * blockDim.x + threadIdx.x;
    int n = t >> 5, c = t & 31;
    if (n >= kN) return;
    float v = x1[n * kHid + c] * W2[c];
#pragma unroll
    for (int off = 16; off >= 1; off >>= 1) v += __shfl_xor(v, off, 64);
    if (c == 0) h2[n] = v;
}

// ---- layer 2 edge passes (1 head, scalar channel) ----
__global__ void k_edge_max2(const int* __restrict__ ei, int E, const float* __restrict__ h2,
                            const float* __restrict__ a_s, const float* __restrict__ a_d,
                            float* __restrict__ emax) {
    int i = blockIdx.x * blockDim.x + threadIdx.x;
    int total = E + kN;
    if (i >= total) return;
    int s, d;
    if (i < E) { s = ei[i]; d = ei[E + i]; } else { s = d = i - E; }
    float e = lrelu(h2[s] * a_s[0] + h2[d] * a_d[0]);
    atomicMaxF(&emax[d], e);
}

__global__ void k_edge_expsum2(const int* __restrict__ ei, int E, const float* __restrict__ h2,
                               const float* __restrict__ a_s, const float* __restrict__ a_d,
                               const float* __restrict__ emax, float* __restrict__ denom) {
    int i = blockIdx.x * blockDim.x + threadIdx.x;
    int total = E + kN;
    if (i >= total) return;
    int s, d;
    if (i < E) { s = ei[i]; d = ei[E + i]; } else { s = d = i - E; }
    float e = lrelu(h2[s] * a_s[0] + h2[d] * a_d[0]);
    atomicAdd(&denom[d], expf(e - emax[d]));
}

__global__ void k_edge_agg2(const int* __restrict__ ei, int E, const float* __restrict__ h2,
                            const float* __restrict__ a_s, const float* __restrict__ a_d,
                            const float* __restrict__ emax, const float* __restrict__ denom,
                            float* __restrict__ acc2) {
    int i = blockIdx.x * blockDim.x + threadIdx.x;
    int total = E + kN;
    if (i >= total) return;
    int s, d;
    if (i < E) { s = ei[i]; d = ei[E + i]; } else { s = d = i - E; }
    float e     = lrelu(h2[s] * a_s[0] + h2[d] * a_d[0]);
    float alpha = expf(e - emax[d]) / denom[d];
    atomicAdd(&acc2[d], h2[s] * alpha);
}

__global__ void k_finish2(const float* __restrict__ acc2, const float* __restrict__ b2,
                          float* __restrict__ out) {
    int n = blockIdx.x * blockDim.x + threadIdx.x;
    if (n >= kN) return;
    out[n] = acc2[n] + b2[0];
}

extern "C" void kernel_launch(void* const* d_in, const int* in_sizes, int n_in,
                              void* d_out, int out_size, void* d_ws, size_t ws_size,
                              hipStream_t stream) {
    const float* x      = (const float*)d_in[0];
    const int*   ei     = (const int*)d_in[1];   // [2,E] int32 (JAX canonicalizes int64)
    const float* W1     = (const float*)d_in[3];
    const float* a_src1 = (const float*)d_in[4];
    const float* a_dst1 = (const float*)d_in[5];
    const float* b1     = (const float*)d_in[6];
    const float* W2     = (const float*)d_in[7];
    const float* a_src2 = (const float*)d_in[8];
    const float* a_dst2 = (const float*)d_in[9];
    const float* b2     = (const float*)d_in[10];
    float* out = (float*)d_out;

    const int E  = in_sizes[1] / 2;
    const int E2 = E + kN;

    // workspace layout (float offsets); total 15.4M floats = 61.6 MB
    float* ws     = (float*)d_ws;
    float* h1     = ws;                 // 6,400,000
    float* x1     = ws + 6400000;       // 1,600,000
    float* asrc1  = ws + 8000000;       //   200,000
    float* adst1  = ws + 8200000;       //   200,000
    float* h2     = ws + 8400000;       //    50,000
    float* denom1 = ws + 8450000;       //   200,000  (zero region start)
    float* acc1   = ws + 8650000;       // 6,400,000
    float* denom2 = ws + 15050000;      //    50,000
    float* acc2   = ws + 15100000;      //    50,000  (zero region end: 6,700,000)
    float* emax1  = ws + 15150000;      //   200,000  (-inf region start)
    float* emax2  = ws + 15350000;      //    50,000  (-inf region end: 250,000)

    const int nzero = 6700000;
    const int ninf  = 250000;
    {
        int blocks = (nzero + 255) / 256;  // covers ninf too
        k_init<<<blocks, 256, 0, stream>>>(denom1, nzero, emax1, ninf);
    }

    k_gemm1<<<kN, 128, 0, stream>>>(x, W1, a_src1, a_dst1, h1, asrc1, adst1);

    {
        int blocks = (E2 + 255) / 256;
        k_edge_max1<<<blocks, 256, 0, stream>>>(ei, E, asrc1, adst1, emax1);
        k_edge_expsum1<<<blocks, 256, 0, stream>>>(ei, E, asrc1, adst1, emax1, denom1);
    }
    {
        unsigned total = (unsigned)E2 * 128u;
        int blocks = (int)((total + 255u) / 256u);
        k_edge_agg1<<<blocks, 256, 0, stream>>>(ei, E, asrc1, adst1, emax1, denom1, h1, acc1);
    }
    k_finish1<<<(kN * kHid + 255) / 256, 256, 0, stream>>>(acc1, b1, x1);

    k_node2<<<(kN * 32 + 255) / 256, 256, 0, stream>>>(x1, W2, h2);
    {
        int blocks = (E2 + 255) / 256;
        k_edge_max2<<<blocks, 256, 0, stream>>>(ei, E, h2, a_src2, a_dst2, emax2);
        k_edge_expsum2<<<blocks, 256, 0, stream>>>(ei, E, h2, a_src2, a_dst2, emax2, denom2);
        k_edge_agg2<<<blocks, 256, 0, stream>>>(ei, E, h2, a_src2, a_dst2, emax2, denom2, acc2);
    }
    k_finish2<<<(kN + 255) / 256, 256, 0, stream>>>(acc2, b2, out);
}

// Round 2
// 307.119 us; speedup vs baseline: 3.0524x; 3.0524x over previous
//
#include <hip/hip_runtime.h>
#include <math.h>

static constexpr int kN     = 50000;
static constexpr int kFIn   = 128;
static constexpr int kHid   = 32;
static constexpr int kHeads = 4;
static constexpr int kScanB = 256;
static constexpr int kScanNB = (kN + kScanB - 1) / kScanB;   // 196

__device__ __forceinline__ float lrelu(float x) { return x > 0.f ? x : 0.2f * x; }

// ---- init: zero deg + cnt (contiguous) ----
__global__ void k_init(int* __restrict__ p, int n) {
    int i = blockIdx.x * blockDim.x + threadIdx.x;
    if (i < n) p[i] = 0;
}

// ---- layer 1 node transform: h1 = x@W1, plus per-head attention logits ----
__global__ void k_gemm1(const float* __restrict__ x, const float* __restrict__ W1,
                        const float* __restrict__ a_src1, const float* __restrict__ a_dst1,
                        float* __restrict__ h1, float* __restrict__ asrc, float* __restrict__ adst) {
    const int n = blockIdx.x;
    const int j = threadIdx.x;            // 0..127 ; head = j>>5
    __shared__ float xs[kFIn];
    xs[j] = x[n * kFIn + j];
    __syncthreads();
    float acc = 0.f;
#pragma unroll 8
    for (int k = 0; k < kFIn; ++k) acc += xs[k] * W1[k * 128 + j];
    h1[n * 128 + j] = acc;
    float ps = acc * a_src1[j];
    float pd = acc * a_dst1[j];
#pragma unroll
    for (int off = 16; off >= 1; off >>= 1) {
        ps += __shfl_xor(ps, off, 64);
        pd += __shfl_xor(pd, off, 64);
    }
    if ((j & 31) == 0) {
        asrc[n * kHeads + (j >> 5)] = ps;
        adst[n * kHeads + (j >> 5)] = pd;
    }
}

// ---- CSR build ----
__global__ void k_hist(const int* __restrict__ ei, int E, int* __restrict__ deg) {
    int i = blockIdx.x * blockDim.x + threadIdx.x;
    int total = E + kN;
    if (i >= total) return;
    int d = (i < E) ? ei[E + i] : (i - E);
    atomicAdd(&deg[d], 1);
}

__global__ void k_scan_a(const int* __restrict__ deg, int* __restrict__ loc, int* __restrict__ bsum) {
    __shared__ int tmp[kScanB];
    int t = threadIdx.x;
    int i = blockIdx.x * kScanB + t;
    int v = (i < kN) ? deg[i] : 0;
    tmp[t] = v;
    __syncthreads();
    for (int off = 1; off < kScanB; off <<= 1) {
        int add = (t >= off) ? tmp[t - off] : 0;
        __syncthreads();
        tmp[t] += add;
        __syncthreads();
    }
    if (i < kN) loc[i] = tmp[t] - v;     // exclusive within block
    if (t == kScanB - 1) bsum[blockIdx.x] = tmp[t];
}

__global__ void k_scan_b(int* __restrict__ bsum) {
    if (threadIdx.x == 0) {
        int run = 0;
        for (int b = 0; b < kScanNB; ++b) { int v = bsum[b]; bsum[b] = run; run += v; }
    }
}

__global__ void k_scan_c(const int* __restrict__ loc, const int* __restrict__ bsum,
                         int* __restrict__ rowptr, int E2) {
    int i = blockIdx.x * kScanB + threadIdx.x;
    if (i < kN) rowptr[i] = loc[i] + bsum[blockIdx.x];
    if (i == 0) rowptr[kN] = E2;
}

// ---- scatter: bucket edges by dst; precompute per-edge softmax weights (4 heads) ----
__global__ void k_scatter(const int* __restrict__ ei, int E,
                          const float* __restrict__ asrc, const float* __restrict__ adst,
                          const int* __restrict__ rowptr, int* __restrict__ cnt,
                          int* __restrict__ es, float* __restrict__ w1) {
    int i = blockIdx.x * blockDim.x + threadIdx.x;
    int total = E + kN;
    if (i >= total) return;
    int s, d;
    if (i < E) { s = ei[i]; d = ei[E + i]; } else { s = d = i - E; }
    int pos = rowptr[d] + atomicAdd(&cnt[d], 1);
    es[pos] = s;
#pragma unroll
    for (int h = 0; h < kHeads; ++h) {
        float e = lrelu(asrc[s * kHeads + h] + adst[d * kHeads + h]);
        w1[pos * 4 + h] = expf(e);       // no max-subtract: |e| is O(10), safe in fp32
    }
}

// ---- layer 1 aggregation (gather, no atomics) + mean/bias/ELU + layer2 matvec ----
__global__ void k_agg1(const int* __restrict__ rowptr, const int* __restrict__ es,
                       const float* __restrict__ w1, const float* __restrict__ h1,
                       const float* __restrict__ b1, const float* __restrict__ W2,
                       float* __restrict__ h2) {
    const int n = blockIdx.x;
    const int j = threadIdx.x;           // channel 0..127, head = j>>5
    const int h = j >> 5;
    const int beg = rowptr[n], end = rowptr[n + 1];
    float acc = 0.f, den = 0.f;
    for (int p = beg; p < end; ++p) {
        int s = es[p];                   // uniform across block -> broadcast
        float w = w1[p * 4 + h];
        acc += w * h1[s * 128 + j];
        den += w;
    }
    __shared__ float sv[128];
    sv[j] = acc / den;
    __syncthreads();
    if (j < 32) {
        float m = 0.25f * (sv[j] + sv[j + 32] + sv[j + 64] + sv[j + 96]) + b1[j];
        m = m > 0.f ? m : expf(m) - 1.f;              // ELU -> x1[n][j]
        float t = m * W2[j];                          // fuse layer-2 matvec
#pragma unroll
        for (int off = 16; off >= 1; off >>= 1) t += __shfl_xor(t, off, 32);
        if (j == 0) h2[n] = t;
    }
}

// ---- layer 2: per-node gather softmax-aggregate, fused bias, writes output ----
__global__ void k_agg2(const int* __restrict__ rowptr, const int* __restrict__ es,
                       const float* __restrict__ h2,
                       const float* __restrict__ a_s2, const float* __restrict__ a_d2,
                       const float* __restrict__ b2, float* __restrict__ out) {
    const int wave = threadIdx.x >> 6;
    const int lane = threadIdx.x & 63;
    const int n = blockIdx.x * 4 + wave;
    if (n >= kN) return;
    const float as = a_s2[0], ad = a_d2[0];
    const int beg = rowptr[n], end = rowptr[n + 1];
    const float hd = h2[n] * ad;
    float sw = 0.f, swh = 0.f;
    for (int p = beg + lane; p < end; p += 64) {
        float hs = h2[es[p]];
        float w = expf(lrelu(hs * as + hd));
        sw += w;
        swh += w * hs;
    }
#pragma unroll
    for (int off = 32; off >= 1; off >>= 1) {
        sw  += __shfl_xor(sw, off, 64);
        swh += __shfl_xor(swh, off, 64);
    }
    if (lane == 0) out[n] = swh / sw + b2[0];
}

extern "C" void kernel_launch(void* const* d_in, const int* in_sizes, int n_in,
                              void* d_out, int out_size, void* d_ws, size_t ws_size,
                              hipStream_t stream) {
    const float* x      = (const float*)d_in[0];
    const int*   ei     = (const int*)d_in[1];
    const float* W1     = (const float*)d_in[3];
    const float* a_src1 = (const float*)d_in[4];
    const float* a_dst1 = (const float*)d_in[5];
    const float* b1     = (const float*)d_in[6];
    const float* W2     = (const float*)d_in[7];
    const float* a_src2 = (const float*)d_in[8];
    const float* a_dst2 = (const float*)d_in[9];
    const float* b2     = (const float*)d_in[10];
    float* out = (float*)d_out;

    const int E  = in_sizes[1] / 2;      // 800000
    const int E2 = E + kN;               // 850000

    // workspace layout
    float* ws    = (float*)d_ws;
    float* h1    = ws;                   // 6,400,000 f
    float* asrc  = ws + 6400000;         //   200,000 f
    float* adst  = ws + 6600000;         //   200,000 f
    float* h2    = ws + 6800000;         //    50,000 f
    float* w1    = ws + 6850000;         // 3,400,000 f
    int*   ibase = (int*)(ws + 10250000);
    int*   es     = ibase;               //   850,000 i
    int*   deg    = ibase + 850000;      //    50,000 i
    int*   cnt    = ibase + 900000;      //    50,000 i
    int*   loc    = ibase + 950000;      //    50,000 i
    int*   rowptr = ibase + 1000000;     //    50,001 i
    int*   bsum   = ibase + 1050016;     //       256 i

    k_init<<<(100000 + 255) / 256, 256, 0, stream>>>(deg, 100000);  // deg+cnt contiguous

    k_hist<<<(E2 + 255) / 256, 256, 0, stream>>>(ei, E, deg);
    k_scan_a<<<kScanNB, kScanB, 0, stream>>>(deg, loc, bsum);
    k_scan_b<<<1, 64, 0, stream>>>(bsum);
    k_scan_c<<<kScanNB, kScanB, 0, stream>>>(loc, bsum, rowptr, E2);

    k_gemm1<<<kN, 128, 0, stream>>>(x, W1, a_src1, a_dst1, h1, asrc, adst);

    k_scatter<<<(E2 + 255) / 256, 256, 0, stream>>>(ei, E, asrc, adst, rowptr, cnt, es, w1);

    k_agg1<<<kN, 128, 0, stream>>>(rowptr, es, w1, h1, b1, W2, h2);

    k_agg2<<<(kN + 3) / 4, 256, 0, stream>>>(rowptr, es, h2, a_src2, a_dst2, b2, out);
}

// Round 3
// 284.968 us; speedup vs baseline: 3.2897x; 1.0777x over previous
//
#include <hip/hip_runtime.h>
#include <math.h>

static constexpr int kN     = 50000;
static constexpr int kFIn   = 128;
static constexpr int kHid   = 32;
static constexpr int kHeads = 4;
static constexpr int kScanB = 256;
static constexpr int kScanNB = (kN + kScanB - 1) / kScanB;   // 196

__device__ __forceinline__ float lrelu(float x) { return x > 0.f ? x : 0.2f * x; }

// ---- init: zero deg + cnt (contiguous) ----
__global__ void k_init(int* __restrict__ p, int n) {
    int i = blockIdx.x * blockDim.x + threadIdx.x;
    if (i < n) p[i] = 0;
}

// ---- layer 1 node transform: h1 = x@W1 with W1 staged in LDS (64KB, XOR-swizzled),
//      fused per-head attention logits via in-wave shuffle reductions.
//      256 thr = 4 waves; lane j owns channels j and j+64; 8 nodes per wave per pass.
__global__ __launch_bounds__(256)
void k_gemm1(const float* __restrict__ x, const float* __restrict__ W1,
             const float* __restrict__ a_src1, const float* __restrict__ a_dst1,
             float* __restrict__ h1, float* __restrict__ asrc, float* __restrict__ adst,
             int nPass) {
    __shared__ float wT[128 * 128];          // 64 KB exactly
    const int t = threadIdx.x;
    const int j = t & 63;                    // lane within wave
    const int g = t >> 6;                    // wave id 0..3
    // stage W1 transposed + swizzled: wT[j*128 + (k ^ ((j&7)<<2))] = W1[k*128 + j]
    for (int idx = t; idx < 128 * 128; idx += 256) {
        int kk = idx >> 7, jj = idx & 127;   // jj fast -> coalesced global read
        wT[jj * 128 + (kk ^ ((jj & 7) << 2))] = W1[kk * 128 + jj];
    }
    const float as0 = a_src1[j], as1 = a_src1[j + 64];
    const float ad0 = a_dst1[j], ad1 = a_dst1[j + 64];
    __syncthreads();

    const int sw0 = (j & 7) << 2;            // swizzle for channel j (and j+64: same)
    for (int pass = blockIdx.x; pass < nPass; pass += gridDim.x) {
        const int base = pass * 32 + g * 8;  // 8 nodes for this wave
        float acc[2][8] = {};
#pragma unroll 8
        for (int k0 = 0; k0 < 128; k0 += 4) {
            const float4 w0 = *(const float4*)&wT[j * 128 + (k0 ^ sw0)];
            const float4 w1v = *(const float4*)&wT[(j + 64) * 128 + (k0 ^ sw0)];
#pragma unroll
            for (int nn = 0; nn < 8; ++nn) {
                int n = base + nn; if (n >= kN) n = kN - 1;          // clamp (guarded stores)
                const float4 xv = *(const float4*)&x[(size_t)n * 128 + k0]; // wave-broadcast
                acc[0][nn] += w0.x * xv.x + w0.y * xv.y + w0.z * xv.z + w0.w * xv.w;
                acc[1][nn] += w1v.x * xv.x + w1v.y * xv.y + w1v.z * xv.z + w1v.w * xv.w;
            }
        }
#pragma unroll
        for (int nn = 0; nn < 8; ++nn) {
            const int n = base + nn;
            const bool valid = (n < kN);
            if (valid) {
                h1[(size_t)n * 128 + j]      = acc[0][nn];
                h1[(size_t)n * 128 + 64 + j] = acc[1][nn];
            }
            float ps0 = acc[0][nn] * as0, ps1 = acc[1][nn] * as1;
            float pd0 = acc[0][nn] * ad0, pd1 = acc[1][nn] * ad1;
#pragma unroll
            for (int off = 16; off >= 1; off >>= 1) {
                ps0 += __shfl_xor(ps0, off, 64);
                ps1 += __shfl_xor(ps1, off, 64);
                pd0 += __shfl_xor(pd0, off, 64);
                pd1 += __shfl_xor(pd1, off, 64);
            }
            if (valid && ((j & 31) == 0)) {
                const int h01 = j >> 5;                 // 0 (lanes 0..31) or 1 (32..63)
                asrc[n * 4 + h01]     = ps0;            // heads 0/1 from channels 0..63
                asrc[n * 4 + 2 + h01] = ps1;            // heads 2/3 from channels 64..127
                adst[n * 4 + h01]     = pd0;
                adst[n * 4 + 2 + h01] = pd1;
            }
        }
    }
}

// ---- CSR build ----
__global__ void k_hist(const int* __restrict__ ei, int E, int* __restrict__ deg) {
    int i = blockIdx.x * blockDim.x + threadIdx.x;
    int total = E + kN;
    if (i >= total) return;
    int d = (i < E) ? ei[E + i] : (i - E);
    atomicAdd(&deg[d], 1);
}

__global__ void k_scan_a(const int* __restrict__ deg, int* __restrict__ loc, int* __restrict__ bsum) {
    __shared__ int tmp[kScanB];
    int t = threadIdx.x;
    int i = blockIdx.x * kScanB + t;
    int v = (i < kN) ? deg[i] : 0;
    tmp[t] = v;
    __syncthreads();
    for (int off = 1; off < kScanB; off <<= 1) {
        int add = (t >= off) ? tmp[t - off] : 0;
        __syncthreads();
        tmp[t] += add;
        __syncthreads();
    }
    if (i < kN) loc[i] = tmp[t] - v;     // exclusive within block
    if (t == kScanB - 1) bsum[blockIdx.x] = tmp[t];
}

__global__ void k_scan_b(int* __restrict__ bsum) {
    if (threadIdx.x == 0) {
        int run = 0;
        for (int b = 0; b < kScanNB; ++b) { int v = bsum[b]; bsum[b] = run; run += v; }
    }
}

__global__ void k_scan_c(const int* __restrict__ loc, const int* __restrict__ bsum,
                         int* __restrict__ rowptr, int E2) {
    int i = blockIdx.x * kScanB + threadIdx.x;
    if (i < kN) rowptr[i] = loc[i] + bsum[blockIdx.x];
    if (i == 0) rowptr[kN] = E2;
}

// ---- scatter: bucket edges by dst; precompute per-edge softmax weights (4 heads) ----
__global__ void k_scatter(const int* __restrict__ ei, int E,
                          const float* __restrict__ asrc, const float* __restrict__ adst,
                          const int* __restrict__ rowptr, int* __restrict__ cnt,
                          int* __restrict__ es, float* __restrict__ w1) {
    int i = blockIdx.x * blockDim.x + threadIdx.x;
    int total = E + kN;
    if (i >= total) return;
    int s, d;
    if (i < E) { s = ei[i]; d = ei[E + i]; } else { s = d = i - E; }
    int pos = rowptr[d] + atomicAdd(&cnt[d], 1);
    es[pos] = s;
#pragma unroll
    for (int h = 0; h < kHeads; ++h) {
        float e = lrelu(asrc[s * kHeads + h] + adst[d * kHeads + h]);
        w1[pos * 4 + h] = expf(e);       // no max-subtract: |e| is O(10), safe in fp32
    }
}

// ---- layer 1 aggregation (gather, no atomics) + mean/bias/ELU + layer2 matvec ----
__global__ void k_agg1(const int* __restrict__ rowptr, const int* __restrict__ es,
                       const float* __restrict__ w1, const float* __restrict__ h1,
                       const float* __restrict__ b1, const float* __restrict__ W2,
                       float* __restrict__ h2) {
    const int n = blockIdx.x;
    const int j = threadIdx.x;           // channel 0..127, head = j>>5
    const int h = j >> 5;
    const int beg = rowptr[n], end = rowptr[n + 1];
    float acc = 0.f, den = 0.f;
    for (int p = beg; p < end; ++p) {
        int s = es[p];                   // uniform across block -> broadcast
        float w = w1[p * 4 + h];
        acc += w * h1[s * 128 + j];
        den += w;
    }
    __shared__ float sv[128];
    sv[j] = acc / den;
    __syncthreads();
    if (j < 32) {
        float m = 0.25f * (sv[j] + sv[j + 32] + sv[j + 64] + sv[j + 96]) + b1[j];
        m = m > 0.f ? m : expf(m) - 1.f;              // ELU -> x1[n][j]
        float t = m * W2[j];                          // fuse layer-2 matvec
#pragma unroll
        for (int off = 16; off >= 1; off >>= 1) t += __shfl_xor(t, off, 32);
        if (j == 0) h2[n] = t;
    }
}

// ---- layer 2: per-node gather softmax-aggregate, fused bias, writes output ----
__global__ void k_agg2(const int* __restrict__ rowptr, const int* __restrict__ es,
                       const float* __restrict__ h2,
                       const float* __restrict__ a_s2, const float* __restrict__ a_d2,
                       const float* __restrict__ b2, float* __restrict__ out) {
    const int wave = threadIdx.x >> 6;
    const int lane = threadIdx.x & 63;
    const int n = blockIdx.x * 4 + wave;
    if (n >= kN) return;
    const float as = a_s2[0], ad = a_d2[0];
    const int beg = rowptr[n], end = rowptr[n + 1];
    const float hd = h2[n] * ad;
    float sw = 0.f, swh = 0.f;
    for (int p = beg + lane; p < end; p += 64) {
        float hs = h2[es[p]];
        float w = expf(lrelu(hs * as + hd));
        sw += w;
        swh += w * hs;
    }
#pragma unroll
    for (int off = 32; off >= 1; off >>= 1) {
        sw  += __shfl_xor(sw, off, 64);
        swh += __shfl_xor(swh, off, 64);
    }
    if (lane == 0) out[n] = swh / sw + b2[0];
}

extern "C" void kernel_launch(void* const* d_in, const int* in_sizes, int n_in,
                              void* d_out, int out_size, void* d_ws, size_t ws_size,
                              hipStream_t stream) {
    const float* x      = (const float*)d_in[0];
    const int*   ei     = (const int*)d_in[1];
    const float* W1     = (const float*)d_in[3];
    const float* a_src1 = (const float*)d_in[4];
    const float* a_dst1 = (const float*)d_in[5];
    const float* b1     = (const float*)d_in[6];
    const float* W2     = (const float*)d_in[7];
    const float* a_src2 = (const float*)d_in[8];
    const float* a_dst2 = (const float*)d_in[9];
    const float* b2     = (const float*)d_in[10];
    float* out = (float*)d_out;

    const int E  = in_sizes[1] / 2;      // 800000
    const int E2 = E + kN;               // 850000

    // workspace layout
    float* ws    = (float*)d_ws;
    float* h1    = ws;                   // 6,400,000 f
    float* asrc  = ws + 6400000;         //   200,000 f
    float* adst  = ws + 6600000;         //   200,000 f
    float* h2    = ws + 6800000;         //    50,000 f
    float* w1    = ws + 6850000;         // 3,400,000 f
    int*   ibase = (int*)(ws + 10250000);
    int*   es     = ibase;               //   850,000 i
    int*   deg    = ibase + 850000;      //    50,000 i
    int*   cnt    = ibase + 900000;      //    50,000 i
    int*   loc    = ibase + 950000;      //    50,000 i
    int*   rowptr = ibase + 1000000;     //    50,001 i
    int*   bsum   = ibase + 1050016;     //       256 i

    k_init<<<(100000 + 255) / 256, 256, 0, stream>>>(deg, 100000);  // deg+cnt contiguous

    k_hist<<<(E2 + 255) / 256, 256, 0, stream>>>(ei, E, deg);
    k_scan_a<<<kScanNB, kScanB, 0, stream>>>(deg, loc, bsum);
    k_scan_b<<<1, 64, 0, stream>>>(bsum);
    k_scan_c<<<kScanNB, kScanB, 0, stream>>>(loc, bsum, rowptr, E2);

    {
        const int nPass = (kN + 31) / 32;    // 1563
        k_gemm1<<<512, 256, 0, stream>>>(x, W1, a_src1, a_dst1, h1, asrc, adst, nPass);
    }

    k_scatter<<<(E2 + 255) / 256, 256, 0, stream>>>(ei, E, asrc, adst, rowptr, cnt, es, w1);

    k_agg1<<<kN, 128, 0, stream>>>(rowptr, es, w1, h1, b1, W2, h2);

    k_agg2<<<(kN + 3) / 4, 256, 0, stream>>>(rowptr, es, h2, a_src2, a_dst2, b2, out);
}

// Round 4
// 251.629 us; speedup vs baseline: 3.7255x; 1.1325x over previous
//
#include <hip/hip_runtime.h>
#include <hip/hip_fp16.h>
#include <math.h>

static constexpr int kN     = 50000;
static constexpr int kFIn   = 128;
static constexpr int kHeads = 4;
static constexpr int kScanB = 256;
static constexpr int kScanNB = (kN + kScanB - 1) / kScanB;   // 196

__device__ __forceinline__ float lrelu(float x) { return x > 0.f ? x : 0.2f * x; }

// ---- init: zero deg + cnt (contiguous) ----
__global__ void k_init(int* __restrict__ p, int n) {
    int i = blockIdx.x * blockDim.x + threadIdx.x;
    if (i < n) p[i] = 0;
}

// ---- layer 1 node transform: h1 = x@W1 (fp16 out), W1 staged in LDS (64KB, swizzled),
//      fused per-head attention logits (fp32) via in-wave shuffle reductions.
__global__ __launch_bounds__(256)
void k_gemm1(const float* __restrict__ x, const float* __restrict__ W1,
             const float* __restrict__ a_src1, const float* __restrict__ a_dst1,
             __half* __restrict__ h1h, float* __restrict__ asrc, float* __restrict__ adst,
             int nPass) {
    __shared__ float wT[128 * 128];          // 64 KB exactly
    const int t = threadIdx.x;
    const int j = t & 63;                    // lane within wave
    const int g = t >> 6;                    // wave id 0..3
    for (int idx = t; idx < 128 * 128; idx += 256) {
        int kk = idx >> 7, jj = idx & 127;   // jj fast -> coalesced global read
        wT[jj * 128 + (kk ^ ((jj & 7) << 2))] = W1[kk * 128 + jj];
    }
    const float as0 = a_src1[j], as1 = a_src1[j + 64];
    const float ad0 = a_dst1[j], ad1 = a_dst1[j + 64];
    __syncthreads();

    const int sw0 = (j & 7) << 2;
    for (int pass = blockIdx.x; pass < nPass; pass += gridDim.x) {
        const int base = pass * 32 + g * 8;  // 8 nodes for this wave
        float acc[2][8] = {};
#pragma unroll 8
        for (int k0 = 0; k0 < 128; k0 += 4) {
            const float4 w0 = *(const float4*)&wT[j * 128 + (k0 ^ sw0)];
            const float4 w1v = *(const float4*)&wT[(j + 64) * 128 + (k0 ^ sw0)];
#pragma unroll
            for (int nn = 0; nn < 8; ++nn) {
                int n = base + nn; if (n >= kN) n = kN - 1;
                const float4 xv = *(const float4*)&x[(size_t)n * 128 + k0]; // wave-broadcast
                acc[0][nn] += w0.x * xv.x + w0.y * xv.y + w0.z * xv.z + w0.w * xv.w;
                acc[1][nn] += w1v.x * xv.x + w1v.y * xv.y + w1v.z * xv.z + w1v.w * xv.w;
            }
        }
#pragma unroll
        for (int nn = 0; nn < 8; ++nn) {
            const int n = base + nn;
            const bool valid = (n < kN);
            if (valid) {
                h1h[(size_t)n * 128 + j]      = __float2half(acc[0][nn]);
                h1h[(size_t)n * 128 + 64 + j] = __float2half(acc[1][nn]);
            }
            float ps0 = acc[0][nn] * as0, ps1 = acc[1][nn] * as1;
            float pd0 = acc[0][nn] * ad0, pd1 = acc[1][nn] * ad1;
#pragma unroll
            for (int off = 16; off >= 1; off >>= 1) {
                ps0 += __shfl_xor(ps0, off, 64);
                ps1 += __shfl_xor(ps1, off, 64);
                pd0 += __shfl_xor(pd0, off, 64);
                pd1 += __shfl_xor(pd1, off, 64);
            }
            if (valid && ((j & 31) == 0)) {
                const int h01 = j >> 5;
                asrc[n * 4 + h01]     = ps0;
                asrc[n * 4 + 2 + h01] = ps1;
                adst[n * 4 + h01]     = pd0;
                adst[n * 4 + 2 + h01] = pd1;
            }
        }
    }
}

// ---- CSR build ----
__global__ void k_hist(const int* __restrict__ ei, int E, int* __restrict__ deg) {
    int i = blockIdx.x * blockDim.x + threadIdx.x;
    int total = E + kN;
    if (i >= total) return;
    int d = (i < E) ? ei[E + i] : (i - E);
    atomicAdd(&deg[d], 1);
}

__global__ void k_scan_a(const int* __restrict__ deg, int* __restrict__ loc, int* __restrict__ bsum) {
    __shared__ int tmp[kScanB];
    int t = threadIdx.x;
    int i = blockIdx.x * kScanB + t;
    int v = (i < kN) ? deg[i] : 0;
    tmp[t] = v;
    __syncthreads();
    for (int off = 1; off < kScanB; off <<= 1) {
        int add = (t >= off) ? tmp[t - off] : 0;
        __syncthreads();
        tmp[t] += add;
        __syncthreads();
    }
    if (i < kN) loc[i] = tmp[t] - v;     // exclusive within block
    if (t == kScanB - 1) bsum[blockIdx.x] = tmp[t];
}

// parallel exclusive scan of the 196 block sums (one 256-thread block)
__global__ void k_scan_b(int* __restrict__ bsum) {
    __shared__ int tmp[256];
    int t = threadIdx.x;
    int v = (t < kScanNB) ? bsum[t] : 0;
    tmp[t] = v;
    __syncthreads();
    for (int off = 1; off < 256; off <<= 1) {
        int add = (t >= off) ? tmp[t - off] : 0;
        __syncthreads();
        tmp[t] += add;
        __syncthreads();
    }
    if (t < kScanNB) bsum[t] = tmp[t] - v;   // exclusive
}

__global__ void k_scan_c(const int* __restrict__ loc, const int* __restrict__ bsum,
                         int* __restrict__ rowptr, int E2) {
    int i = blockIdx.x * kScanB + threadIdx.x;
    if (i < kN) rowptr[i] = loc[i] + bsum[blockIdx.x];
    if (i == 0) rowptr[kN] = E2;
}

// ---- scatter: bucket edge sources by dst (es only; weights recomputed in agg1) ----
__global__ void k_scatter(const int* __restrict__ ei, int E,
                          const int* __restrict__ rowptr, int* __restrict__ cnt,
                          int* __restrict__ es) {
    int i = blockIdx.x * blockDim.x + threadIdx.x;
    int total = E + kN;
    if (i >= total) return;
    int s, d;
    if (i < E) { s = ei[i]; d = ei[E + i]; } else { s = d = i - E; }
    int pos = rowptr[d] + atomicAdd(&cnt[d], 1);
    es[pos] = s;
}

// ---- layer 1 aggregation: 1 wave per node, lane = 2 channels (half2 gather),
//      softmax weights recomputed from L2-resident asrc/adst; epilogue fully in-register:
//      head-mean + bias + ELU + layer-2 matvec -> h2[n]. No LDS, no atomics.
__global__ __launch_bounds__(256)
void k_agg1(const int* __restrict__ rowptr, const int* __restrict__ es,
            const float* __restrict__ asrc, const float* __restrict__ adst,
            const __half* __restrict__ h1h, const float* __restrict__ b1,
            const float* __restrict__ W2, float* __restrict__ h2) {
    const int n = blockIdx.x * 4 + (threadIdx.x >> 6);
    if (n >= kN) return;
    const int j  = threadIdx.x & 63;     // lane: channels 2j, 2j+1
    const int hh = j >> 4;               // head of both channels
    const float adv = adst[n * 4 + hh];
    const int beg = rowptr[n], end = rowptr[n + 1];
    float ax0 = 0.f, ay0 = 0.f, dn0 = 0.f;
    float ax1 = 0.f, ay1 = 0.f, dn1 = 0.f;
    int p = beg;
    for (; p + 2 <= end; p += 2) {
        const int s0 = es[p], s1 = es[p + 1];
        const float e0 = asrc[s0 * 4 + hh] + adv;
        const float e1 = asrc[s1 * 4 + hh] + adv;
        const __half2 v0 = *(const __half2*)&h1h[(size_t)s0 * 128 + 2 * j];
        const __half2 v1 = *(const __half2*)&h1h[(size_t)s1 * 128 + 2 * j];
        const float w0 = expf(lrelu(e0));
        const float w1 = expf(lrelu(e1));
        const float2 f0 = __half22float2(v0);
        const float2 f1 = __half22float2(v1);
        ax0 += w0 * f0.x; ay0 += w0 * f0.y; dn0 += w0;
        ax1 += w1 * f1.x; ay1 += w1 * f1.y; dn1 += w1;
    }
    if (p < end) {
        const int s0 = es[p];
        const float e0 = asrc[s0 * 4 + hh] + adv;
        const __half2 v0 = *(const __half2*)&h1h[(size_t)s0 * 128 + 2 * j];
        const float w0 = expf(lrelu(e0));
        const float2 f0 = __half22float2(v0);
        ax0 += w0 * f0.x; ay0 += w0 * f0.y; dn0 += w0;
    }
    const float den = dn0 + dn1;
    float vx = (ax0 + ax1) / den;
    float vy = (ay0 + ay1) / den;
    // mean over heads: lanes {j, j^16, j^32, j^48} hold the 4 heads of channel pair (j&15)
    vx += __shfl_xor(vx, 32, 64); vy += __shfl_xor(vy, 32, 64);
    vx += __shfl_xor(vx, 16, 64); vy += __shfl_xor(vy, 16, 64);
    const int m = j & 15;                // channel pair (2m, 2m+1)
    float u0 = 0.25f * vx + b1[2 * m];
    float u1 = 0.25f * vy + b1[2 * m + 1];
    u0 = u0 > 0.f ? u0 : expf(u0) - 1.f;
    u1 = u1 > 0.f ? u1 : expf(u1) - 1.f;
    float tsum = u0 * W2[2 * m] + u1 * W2[2 * m + 1];
    tsum += __shfl_xor(tsum, 8, 64);
    tsum += __shfl_xor(tsum, 4, 64);
    tsum += __shfl_xor(tsum, 2, 64);
    tsum += __shfl_xor(tsum, 1, 64);
    if (j == 0) h2[n] = tsum;
}

// ---- layer 2: 16 lanes per node, gather h2 (L2-resident), fused bias -> out ----
__global__ __launch_bounds__(256)
void k_agg2(const int* __restrict__ rowptr, const int* __restrict__ es,
            const float* __restrict__ h2,
            const float* __restrict__ a_s2, const float* __restrict__ a_d2,
            const float* __restrict__ b2, float* __restrict__ out) {
    const int n = blockIdx.x * 16 + (threadIdx.x >> 4);
    if (n >= kN) return;
    const int l = threadIdx.x & 15;
    const float as = a_s2[0], ad = a_d2[0];
    const int beg = rowptr[n], end = rowptr[n + 1];
    const float hd = h2[n] * ad;
    float sw = 0.f, swh = 0.f;
    for (int p = beg + l; p < end; p += 16) {
        float hs = h2[es[p]];
        float w = expf(lrelu(hs * as + hd));
        sw += w;
        swh += w * hs;
    }
#pragma unroll
    for (int off = 8; off >= 1; off >>= 1) {
        sw  += __shfl_xor(sw, off, 64);
        swh += __shfl_xor(swh, off, 64);
    }
    if (l == 0) out[n] = swh / sw + b2[0];
}

extern "C" void kernel_launch(void* const* d_in, const int* in_sizes, int n_in,
                              void* d_out, int out_size, void* d_ws, size_t ws_size,
                              hipStream_t stream) {
    const float* x      = (const float*)d_in[0];
    const int*   ei     = (const int*)d_in[1];
    const float* W1     = (const float*)d_in[3];
    const float* a_src1 = (const float*)d_in[4];
    const float* a_dst1 = (const float*)d_in[5];
    const float* b1     = (const float*)d_in[6];
    const float* W2     = (const float*)d_in[7];
    const float* a_src2 = (const float*)d_in[8];
    const float* a_dst2 = (const float*)d_in[9];
    const float* b2     = (const float*)d_in[10];
    float* out = (float*)d_out;

    const int E  = in_sizes[1] / 2;      // 800000
    const int E2 = E + kN;               // 850000

    // workspace layout (float offsets)
    float*  ws    = (float*)d_ws;
    float*  asrc  = ws;                          //   200,000 f
    float*  adst  = ws + 200000;                 //   200,000 f
    float*  h2    = ws + 400000;                 //    50,000 f
    __half* h1h   = (__half*)(ws + 450000);      // 6,400,000 h = 3,200,000 f
    int*    ibase = (int*)(ws + 3650000);
    int*    es     = ibase;                      //   850,000 i
    int*    deg    = ibase + 850000;             //    50,000 i
    int*    cnt    = ibase + 900000;             //    50,000 i
    int*    loc    = ibase + 950000;             //    50,000 i
    int*    rowptr = ibase + 1000000;            //    50,001 i
    int*    bsum   = ibase + 1050016;            //       256 i

    k_init<<<(100000 + 255) / 256, 256, 0, stream>>>(deg, 100000);  // deg+cnt contiguous

    k_hist<<<(E2 + 255) / 256, 256, 0, stream>>>(ei, E, deg);
    k_scan_a<<<kScanNB, kScanB, 0, stream>>>(deg, loc, bsum);
    k_scan_b<<<1, 256, 0, stream>>>(bsum);
    k_scan_c<<<kScanNB, kScanB, 0, stream>>>(loc, bsum, rowptr, E2);

    {
        const int nPass = (kN + 31) / 32;    // 1563
        k_gemm1<<<512, 256, 0, stream>>>(x, W1, a_src1, a_dst1, h1h, asrc, adst, nPass);
    }

    k_scatter<<<(E2 + 255) / 256, 256, 0, stream>>>(ei, E, rowptr, cnt, es);

    k_agg1<<<(kN + 3) / 4, 256, 0, stream>>>(rowptr, es, asrc, adst, h1h, b1, W2, h2);

    k_agg2<<<(kN + 15) / 16, 256, 0, stream>>>(rowptr, es, h2, a_src2, a_dst2, b2, out);
}